// Round 13
// baseline (2123.605 us; speedup 1.0000x reference)
//
#include <hip/hip_runtime.h>
#include <hip/hip_cooperative_groups.h>

namespace cg = cooperative_groups;

#define EPS 1e-5f

typedef __attribute__((ext_vector_type(8))) short s8v;   // 8 x bf16 bits
typedef __attribute__((ext_vector_type(4))) float f4v;   // MFMA accumulator

__device__ __forceinline__ unsigned short f2b(float x) {
  unsigned int u = __float_as_uint(x);
  u += 0x7FFFu + ((u >> 16) & 1u);
  return (unsigned short)(u >> 16);
}
__device__ __forceinline__ float b2f(unsigned short b) {
  return __uint_as_float(((unsigned int)b) << 16);
}

// ===========================================================================
// Cooperative persistent kernel: L1 + 11 mid layers. Grid 504 = 42 x KS(12).
// launch_bounds(256,2): 2 blocks/CU -> 512 co-residency >= 504 under the most
// conservative runtime calc (r12 failed at 588; hypothesis: coop occupancy).
// Phases separated by grid.sync(). Arithmetic identical to the proven r8
// pattern; empty K-chunks (mids ky=11) write zero partial tiles.
// HOST INVARIANTS: kchunk % 64 == 0; KS*kchunk >= K; staged slabs fit lda.
// ===========================================================================
__global__ __launch_bounds__(256, 2)
void coop_chain(const unsigned short* __restrict__ xg,
                const float* __restrict__ W1, const float* __restrict__ b1,
                const float* __restrict__ Wmid, const float* __restrict__ bmid,
                const float* __restrict__ bng, const float* __restrict__ bnb,
                const float* __restrict__ bnrm, const float* __restrict__ bnrv,
                float* __restrict__ dR,
                unsigned short* __restrict__ hA, unsigned short* __restrict__ hB,
                unsigned short* __restrict__ htr,
                unsigned short* __restrict__ Pb)
{
  cg::grid_group grid = cg::this_grid();
  __shared__ unsigned short As[256 * 72];
  __shared__ unsigned short Bs[64 * 72];
  const int bid = (int)blockIdx.x;
  const int t = threadIdx.x, lane = t & 63, w = t >> 6;
  const int lr = lane & 15, lk = lane >> 4;
  const int R = 2666;

  const int ky = bid / 42, ntp = bid % 42;   // ky 0..11
  const int n0 = ntp << 6;
  const int ar = t >> 2, ac = t & 3;
  const int br = t >> 2, bq = t & 3;

  auto gemm = [&](const unsigned short* A, int lda, const float* B, int ldb,
                  int K, int kchunk) {
    const int kstart = ky * kchunk;
    const int kend = min(K, kstart + kchunk);
    const int len = kend - kstart;
    const int nfull = (len > 0) ? (len >> 6) : 0;
    const int rem = (len > 0) ? (len & 63) : 0;

    f4v acc[4][4] = {};
    float4 b_cur[4], b_nxt[4];

    auto loadB = [&](float4* dst, int kb) {
      const int row = n0 + br;
      if (row < R) {
        #pragma unroll
        for (int i = 0; i < 4; ++i)
          dst[i] = *(const float4*)(B + (size_t)row * ldb + kb + bq * 16 + i * 4);
      } else {
        #pragma unroll
        for (int i = 0; i < 4; ++i) { dst[i].x = dst[i].y = dst[i].z = dst[i].w = 0.f; }
      }
    };
    auto stageA = [&](int kb) {
      #pragma unroll
      for (int p = 0; p < 4; ++p) {
        const int row = ar + p * 64;
        const s8v v0 = *(const s8v*)(A + (size_t)row * lda + kb + ac * 16);
        const s8v v1 = *(const s8v*)(A + (size_t)row * lda + kb + ac * 16 + 8);
        *(s8v*)(As + row * 72 + ac * 16) = v0;
        *(s8v*)(As + row * 72 + ac * 16 + 8) = v1;
      }
    };
    auto stageB = [&](const float4* bv) {
      s8v p0, p1;
      p0[0] = (short)f2b(bv[0].x); p0[1] = (short)f2b(bv[0].y);
      p0[2] = (short)f2b(bv[0].z); p0[3] = (short)f2b(bv[0].w);
      p0[4] = (short)f2b(bv[1].x); p0[5] = (short)f2b(bv[1].y);
      p0[6] = (short)f2b(bv[1].z); p0[7] = (short)f2b(bv[1].w);
      p1[0] = (short)f2b(bv[2].x); p1[1] = (short)f2b(bv[2].y);
      p1[2] = (short)f2b(bv[2].z); p1[3] = (short)f2b(bv[2].w);
      p1[4] = (short)f2b(bv[3].x); p1[5] = (short)f2b(bv[3].y);
      p1[6] = (short)f2b(bv[3].z); p1[7] = (short)f2b(bv[3].w);
      *(s8v*)(Bs + br * 72 + bq * 16) = p0;
      *(s8v*)(Bs + br * 72 + bq * 16 + 8) = p1;
    };
    auto domfma = [&]() {
      #pragma unroll
      for (int ks = 0; ks < 2; ++ks) {
        s8v af[4], bf[4];
        #pragma unroll
        for (int fm = 0; fm < 4; ++fm)
          af[fm] = *(const s8v*)(As + (w * 64 + fm * 16 + lr) * 72 + ks * 32 + lk * 8);
        #pragma unroll
        for (int fn = 0; fn < 4; ++fn)
          bf[fn] = *(const s8v*)(Bs + (fn * 16 + lr) * 72 + ks * 32 + lk * 8);
        #pragma unroll
        for (int fm = 0; fm < 4; ++fm)
          #pragma unroll
          for (int fn = 0; fn < 4; ++fn)
            acc[fm][fn] = __builtin_amdgcn_mfma_f32_16x16x32_bf16(af[fm], bf[fn], acc[fm][fn], 0, 0, 0);
      }
    };

    int kb = kstart;
    if (nfull > 0) {
      loadB(b_cur, kb);
      for (int s = 0; s < nfull; ++s) {
        stageA(kb);
        stageB(b_cur);
        __syncthreads();
        const bool more = (s + 1 < nfull);
        if (more) loadB(b_nxt, kb + 64);
        domfma();
        __syncthreads();
        if (more) {
          #pragma unroll
          for (int i = 0; i < 4; ++i) b_cur[i] = b_nxt[i];
          kb += 64;
        }
      }
      kb += 64;
    }
    if (rem) {
      stageA(kb);
      {
        const int row = n0 + br;
        #pragma unroll
        for (int i = 0; i < 4; ++i) {
          float e[4];
          #pragma unroll
          for (int v = 0; v < 4; ++v) {
            const int c = kb + bq * 16 + i * 4 + v;
            e[v] = (row < R && c < kend) ? B[(size_t)row * ldb + c] : 0.f;
          }
          b_cur[i].x = e[0]; b_cur[i].y = e[1]; b_cur[i].z = e[2]; b_cur[i].w = e[3];
        }
      }
      stageB(b_cur);
      __syncthreads();
      domfma();
      __syncthreads();
    }

    unsigned short* Pt = Pb + ((size_t)ky * 42 + ntp) * 16384;
    #pragma unroll
    for (int fm = 0; fm < 4; ++fm)
      #pragma unroll
      for (int fn = 0; fn < 4; ++fn) {
        const int col = fn * 16 + lr;
        #pragma unroll
        for (int j = 0; j < 4; ++j) {
          const int row = w * 64 + fm * 16 + lk * 4 + j;
          Pt[row * 64 + col] = f2b(acc[fm][fn][j]);
        }
      }
  };

  auto reduce = [&](const float* bias, const float* g, const float* bb,
                    const float* rm, const float* rv,
                    bool RES, bool WRD, bool WRT, unsigned short* Cb) {
    if (bid >= 168) return;
    const int rntp = bid % 42, qr = bid / 42;
    const int rn0 = rntp << 6;
    const int row = qr * 64 + (t >> 2);
    const int c0 = (t & 3) * 16;

    float vv[16];
    #pragma unroll
    for (int e = 0; e < 16; ++e) vv[e] = 0.f;
    const unsigned short* base = Pb + (size_t)rntp * 16384 + row * 64 + c0;
    for (int kk = 0; kk < 12; ++kk) {
      const s8v pa  = *(const s8v*)(base + (size_t)kk * 42 * 16384);
      const s8v pb2 = *(const s8v*)(base + (size_t)kk * 42 * 16384 + 8);
      #pragma unroll
      for (int e = 0; e < 8; ++e) vv[e]     += b2f((unsigned short)pa[e]);
      #pragma unroll
      for (int e = 0; e < 8; ++e) vv[8 + e] += b2f((unsigned short)pb2[e]);
    }
    unsigned short outp[16];
    #pragma unroll
    for (int e = 0; e < 16; ++e) {
      const int col = rn0 + c0 + e;
      float v = 0.f;
      if (col < R) {
        v = vv[e] + bias[col];
        const float s = g[col] * rsqrtf(rv[col] + EPS);
        v = (v - rm[col]) * s + bb[col];
        v = fmaxf(v, 0.f);
        if (RES) v += dR[(size_t)row * 2688 + col];
        if (WRD) dR[(size_t)row * 2688 + col] = v;
        if (WRT) htr[(size_t)col * 256 + row] = f2b(v);
      }
      outp[e] = f2b(v);
    }
    if (!WRT) {
      *(s8v*)(Cb + (size_t)row * 2688 + rn0 + c0) = *(const s8v*)(outp);
      *(s8v*)(Cb + (size_t)row * 2688 + rn0 + c0 + 8) = *(const s8v*)(outp + 8);
    }
  };

  // L1: K=16384, kchunk=1408 (22x64; ky=11: 15488..16384, 14 steps, rem=0)
  gemm(xg, 16384, W1, 16384, 16384, 1408);
  grid.sync();
  reduce(b1, bng, bnb, bnrm, bnrv, false, true, false, hA);
  grid.sync();

  unsigned short* cur = hA;
  unsigned short* nxt = hB;
  for (int k = 0; k < 11; ++k) {
    // mids: kchunk=256 (ky=10: 2560..2666 nfull=1 rem=42 slab<=2688=lda;
    // ky=11: empty -> zero partial)
    gemm(cur, 2688, Wmid + (size_t)k * R * R, R, R, 256);
    grid.sync();
    const int L = k + 1;
    reduce(bmid + (size_t)k * R,
           bng + (size_t)L * R, bnb + (size_t)L * R,
           bnrm + (size_t)L * R, bnrv + (size_t)L * R,
           (k & 1) != 0, (k & 1) != 0, k == 10, nxt);
    grid.sync();
    unsigned short* tmp = cur; cur = nxt; nxt = tmp;
  }
}

// ===========================================================================
// Fallback / tail split-K GEMM (r8 structure, empty-chunk safe).
// ===========================================================================
__global__ __launch_bounds__(256)
void gemm_bk64(const unsigned short* __restrict__ A, int lda,
               const float* __restrict__ B, int ldb,
               unsigned short* __restrict__ Pb,
               int NPAIR, int N, int K, int kchunk, int KS)
{
  __shared__ unsigned short As[256 * 72];
  __shared__ unsigned short Bs[64 * 72];
  const int bid = (int)blockIdx.x;
  const int ky = bid % KS, ntp = bid / KS;
  const int n0 = ntp << 6;
  const int t = threadIdx.x, lane = t & 63, w = t >> 6;
  const int lr = lane & 15, lk = lane >> 4;

  const int kstart = ky * kchunk;
  const int kend = min(K, kstart + kchunk);
  const int len = kend - kstart;
  const int nfull = (len > 0) ? (len >> 6) : 0;
  const int rem = (len > 0) ? (len & 63) : 0;

  const int ar = t >> 2, ac = t & 3;
  const int br = t >> 2, bq = t & 3;

  f4v acc[4][4] = {};
  float4 b_cur[4], b_nxt[4];

  auto loadB = [&](float4* dst, int kb) {
    const int row = n0 + br;
    if (row < N) {
      #pragma unroll
      for (int i = 0; i < 4; ++i)
        dst[i] = *(const float4*)(B + (size_t)row * ldb + kb + bq * 16 + i * 4);
    } else {
      #pragma unroll
      for (int i = 0; i < 4; ++i) { dst[i].x = dst[i].y = dst[i].z = dst[i].w = 0.f; }
    }
  };
  auto stageA = [&](int kb) {
    #pragma unroll
    for (int p = 0; p < 4; ++p) {
      const int row = ar + p * 64;
      const s8v v0 = *(const s8v*)(A + (size_t)row * lda + kb + ac * 16);
      const s8v v1 = *(const s8v*)(A + (size_t)row * lda + kb + ac * 16 + 8);
      *(s8v*)(As + row * 72 + ac * 16) = v0;
      *(s8v*)(As + row * 72 + ac * 16 + 8) = v1;
    }
  };
  auto stageB = [&](const float4* bv) {
    s8v p0, p1;
    p0[0] = (short)f2b(bv[0].x); p0[1] = (short)f2b(bv[0].y);
    p0[2] = (short)f2b(bv[0].z); p0[3] = (short)f2b(bv[0].w);
    p0[4] = (short)f2b(bv[1].x); p0[5] = (short)f2b(bv[1].y);
    p0[6] = (short)f2b(bv[1].z); p0[7] = (short)f2b(bv[1].w);
    p1[0] = (short)f2b(bv[2].x); p1[1] = (short)f2b(bv[2].y);
    p1[2] = (short)f2b(bv[2].z); p1[3] = (short)f2b(bv[2].w);
    p1[4] = (short)f2b(bv[3].x); p1[5] = (short)f2b(bv[3].y);
    p1[6] = (short)f2b(bv[3].z); p1[7] = (short)f2b(bv[3].w);
    *(s8v*)(Bs + br * 72 + bq * 16) = p0;
    *(s8v*)(Bs + br * 72 + bq * 16 + 8) = p1;
  };
  auto domfma = [&]() {
    #pragma unroll
    for (int ks = 0; ks < 2; ++ks) {
      s8v af[4], bf[4];
      #pragma unroll
      for (int fm = 0; fm < 4; ++fm)
        af[fm] = *(const s8v*)(As + (w * 64 + fm * 16 + lr) * 72 + ks * 32 + lk * 8);
      #pragma unroll
      for (int fn = 0; fn < 4; ++fn)
        bf[fn] = *(const s8v*)(Bs + (fn * 16 + lr) * 72 + ks * 32 + lk * 8);
      #pragma unroll
      for (int fm = 0; fm < 4; ++fm)
        #pragma unroll
        for (int fn = 0; fn < 4; ++fn)
          acc[fm][fn] = __builtin_amdgcn_mfma_f32_16x16x32_bf16(af[fm], bf[fn], acc[fm][fn], 0, 0, 0);
    }
  };

  int kb = kstart;
  if (nfull > 0) {
    loadB(b_cur, kb);
    for (int s = 0; s < nfull; ++s) {
      stageA(kb);
      stageB(b_cur);
      __syncthreads();
      const bool more = (s + 1 < nfull);
      if (more) loadB(b_nxt, kb + 64);
      domfma();
      __syncthreads();
      if (more) {
        #pragma unroll
        for (int i = 0; i < 4; ++i) b_cur[i] = b_nxt[i];
        kb += 64;
      }
    }
    kb += 64;
  }
  if (rem) {
    stageA(kb);
    {
      const int row = n0 + br;
      #pragma unroll
      for (int i = 0; i < 4; ++i) {
        float e[4];
        #pragma unroll
        for (int v = 0; v < 4; ++v) {
          const int c = kb + bq * 16 + i * 4 + v;
          e[v] = (row < N && c < kend) ? B[(size_t)row * ldb + c] : 0.f;
        }
        b_cur[i].x = e[0]; b_cur[i].y = e[1]; b_cur[i].z = e[2]; b_cur[i].w = e[3];
      }
    }
    stageB(b_cur);
    __syncthreads();
    domfma();
    __syncthreads();
  }

  unsigned short* Pt = Pb + ((size_t)ky * NPAIR + ntp) * 16384;
  #pragma unroll
  for (int fm = 0; fm < 4; ++fm)
    #pragma unroll
    for (int fn = 0; fn < 4; ++fn) {
      const int col = fn * 16 + lr;
      #pragma unroll
      for (int j = 0; j < 4; ++j) {
        const int row = w * 64 + fm * 16 + lk * 4 + j;
        Pt[row * 64 + col] = f2b(acc[fm][fn][j]);
      }
    }
}

// Fallback reduce with BN/RES/WRD/WRT (r8 structure).
template<bool BN, bool RES, bool WRD, bool WRT, bool F32OUT>
__global__ __launch_bounds__(256)
void reduce_bk64(const unsigned short* __restrict__ Pb, int KS, int NPAIR, int N,
                 const float* __restrict__ bias,
                 const float* __restrict__ g, const float* __restrict__ bb,
                 const float* __restrict__ rm, const float* __restrict__ rv,
                 float* __restrict__ dR, int lddr,
                 unsigned short* __restrict__ Cb, int ldc,
                 unsigned short* __restrict__ Ct, float* __restrict__ Cf)
{
  const int bid = (int)blockIdx.x;
  const int ntp = bid >> 2, qr = bid & 3;
  const int t = threadIdx.x;
  const int row = qr * 64 + (t >> 2);
  const int c0 = (t & 3) * 16;
  const int n0 = ntp << 6;

  float vv[16];
  #pragma unroll
  for (int e = 0; e < 16; ++e) vv[e] = 0.f;
  const unsigned short* base = Pb + (size_t)ntp * 16384 + row * 64 + c0;
  for (int ky = 0; ky < KS; ++ky) {
    const s8v pa  = *(const s8v*)(base + (size_t)ky * NPAIR * 16384);
    const s8v pb2 = *(const s8v*)(base + (size_t)ky * NPAIR * 16384 + 8);
    #pragma unroll
    for (int e = 0; e < 8; ++e) vv[e]     += b2f((unsigned short)pa[e]);
    #pragma unroll
    for (int e = 0; e < 8; ++e) vv[8 + e] += b2f((unsigned short)pb2[e]);
  }
  unsigned short outp[16];
  #pragma unroll
  for (int e = 0; e < 16; ++e) {
    const int col = n0 + c0 + e;
    float v = 0.f;
    if (col < N) {
      v = vv[e] + bias[col];
      if (BN) { const float s = g[col] * rsqrtf(rv[col] + EPS); v = (v - rm[col]) * s + bb[col]; }
      v = fmaxf(v, 0.f);
      if (RES) v += dR[(size_t)row * lddr + col];
      if (WRD) dR[(size_t)row * lddr + col] = v;
      if (F32OUT) Cf[(size_t)row * N + col] = v;
      else if (WRT) Ct[(size_t)col * 256 + row] = f2b(v);
    }
    outp[e] = f2b(v);
  }
  if (!F32OUT && !WRT) {
    *(s8v*)(Cb + (size_t)row * ldc + n0 + c0) = *(const s8v*)(outp);
    *(s8v*)(Cb + (size_t)row * ldc + n0 + c0 + 8) = *(const s8v*)(outp + 8);
  }
}

// ---------------------------------------------------------------------------
// Prep: pack x-geno to bf16, pack env rows, zero h5b pads (stride 13376).
// ---------------------------------------------------------------------------
__global__ __launch_bounds__(256)
void prep_k(const float* __restrict__ x, unsigned short* __restrict__ xg,
            unsigned short* __restrict__ envb, unsigned short* __restrict__ h5b)
{
  const int bid = (int)blockIdx.x, t = threadIdx.x;
  if (bid < 16384) {
    const int idx = bid * 256 + t;
    const int r = idx >> 14, c = idx & 16383;
    xg[idx] = f2b(x[(size_t)r * 16437 + c]);
  } else if (bid < 16456) {
    const int idx = (bid - 16384) * 256 + t;
    const int b = idx / 72, c = idx % 72;
    envb[idx] = (c < 53) ? f2b(x[(size_t)b * 16437 + 16384 + c]) : (unsigned short)0;
  } else {
    for (int z = t; z < 256 * 46; z += 256) {
      const int b = z / 46, j = z % 46;
      h5b[(size_t)b * 13376 + 13330 + j] = 0;
    }
  }
}

// ---------------------------------------------------------------------------
// Fused head: per unit i, 4 chained 256x64x64 GEMMs in LDS/regs (unchanged).
// ---------------------------------------------------------------------------
__global__ __launch_bounds__(256, 2)
void fused_head(const unsigned short* __restrict__ envb,
                const unsigned short* __restrict__ htr,
                const float* __restrict__ Wlin, const float* __restrict__ blin,
                const float* __restrict__ W13, const float* __restrict__ b13,
                const float* __restrict__ W14, const float* __restrict__ b14,
                const float* __restrict__ W15, const float* __restrict__ b15,
                const float* __restrict__ bn3g, const float* __restrict__ bn3b,
                const float* __restrict__ bn3rm, const float* __restrict__ bn3rv,
                unsigned short* __restrict__ h5b)
{
  __shared__ unsigned short act[256 * 72];
  __shared__ unsigned short Wl[64 * 72];
  __shared__ unsigned short Wa[64 * 72];
  __shared__ unsigned short Wb[16 * 72];
  const int i = (int)blockIdx.x;
  const int t = threadIdx.x, lane = t & 63, w = t >> 6;
  const int lr = lane & 15, lk = lane >> 4;
  const int R = 2666;

  #pragma unroll
  for (int c8 = 0; c8 < 9; ++c8)
    *(s8v*)(act + t * 72 + c8 * 8) = *(const s8v*)(envb + t * 72 + c8 * 8);
  act[t * 72 + 53] = htr[(size_t)i * 256 + t];

  const float* wli = Wlin + (size_t)i * 2916;
  for (int idx = t; idx < 64 * 72; idx += 256) {
    const int r = idx / 72, f = idx % 72;
    Wl[idx] = (r < 54 && f < 54) ? f2b(wli[r * 54 + f]) : (unsigned short)0;
    Wa[idx] = (r < 54 && f < 54) ? f2b(W13[r * 54 + f]) : (unsigned short)0;
  }
  for (int idx = t; idx < 16 * 72; idx += 256) {
    const int r = idx / 72, f = idx % 72;
    Wb[idx] = (r < 5 && f < 54) ? f2b(W15[r * 54 + f]) : (unsigned short)0;
  }
  const float s0 = bn3g[i] * rsqrtf(bn3rv[i] + EPS), m0 = bn3rm[i], c0 = bn3b[i];
  const float s1 = bn3g[R+i] * rsqrtf(bn3rv[R+i] + EPS), m1 = bn3rm[R+i], c1 = bn3b[R+i];
  const float s2 = bn3g[2*R+i] * rsqrtf(bn3rv[2*R+i] + EPS), m2 = bn3rm[2*R+i], c2 = bn3b[2*R+i];
  __syncthreads();

  const int abase = (w * 64 + lr) * 72 + lk * 8;
  f4v acc[4][4];

  auto zacc = [&]() {
    #pragma unroll
    for (int a = 0; a < 4; ++a)
      #pragma unroll
      for (int b = 0; b < 4; ++b) acc[a][b] = f4v{0.f, 0.f, 0.f, 0.f};
  };
  auto gemm4 = [&](const unsigned short* B) {
    s8v af[2][4];
    #pragma unroll
    for (int ks = 0; ks < 2; ++ks)
      #pragma unroll
      for (int fm = 0; fm < 4; ++fm)
        af[ks][fm] = *(const s8v*)(act + abase + fm * 16 * 72 + ks * 32);
    #pragma unroll
    for (int fn = 0; fn < 4; ++fn) {
      s8v b0 = *(const s8v*)(B + (fn * 16 + lr) * 72 + lk * 8);
      s8v b1 = *(const s8v*)(B + (fn * 16 + lr) * 72 + 32 + lk * 8);
      #pragma unroll
      for (int fm = 0; fm < 4; ++fm) {
        acc[fm][fn] = __builtin_amdgcn_mfma_f32_16x16x32_bf16(af[0][fm], b0, acc[fm][fn], 0, 0, 0);
        acc[fm][fn] = __builtin_amdgcn_mfma_f32_16x16x32_bf16(af[1][fm], b1, acc[fm][fn], 0, 0, 0);
      }
    }
  };
  auto epi_bn = [&](const float* bias, float s, float m, float c) {
    #pragma unroll
    for (int fn = 0; fn < 4; ++fn) {
      const int o = fn * 16 + lr;
      const float bo = (o < 54) ? bias[o] : 0.f;
      #pragma unroll
      for (int fm = 0; fm < 4; ++fm)
        #pragma unroll
        for (int j = 0; j < 4; ++j) {
          const int row = w * 64 + fm * 16 + lk * 4 + j;
          float v = acc[fm][fn][j] + bo;
          v = (v - m) * s + c;
          v = fmaxf(v, 0.f);
          act[row * 72 + o] = (o < 54) ? f2b(v) : (unsigned short)0;
        }
    }
  };

  zacc(); gemm4(Wl);
  #pragma unroll
  for (int fn = 0; fn < 4; ++fn) {
    const int o = fn * 16 + lr;
    const float bl = (o < 54) ? blin[(size_t)i * 54 + o] : 0.f;
    #pragma unroll
    for (int fm = 0; fm < 4; ++fm)
      #pragma unroll
      for (int j = 0; j < 4; ++j) {
        const int row = w * 64 + fm * 16 + lk * 4 + j;
        float v = acc[fm][fn][j] + bl;
        act[row * 72 + o] = (o < 54) ? f2b(v) : (unsigned short)0;
      }
  }
  __syncthreads();
  for (int idx = t; idx < 64 * 72; idx += 256) {
    const int r = idx / 72, f = idx % 72;
    Wl[idx] = (r < 54 && f < 54) ? f2b(W14[r * 54 + f]) : (unsigned short)0;
  }
  zacc(); gemm4(Wa); epi_bn(b13, s0, m0, c0);
  __syncthreads();
  zacc(); gemm4(Wl); epi_bn(b14, s1, m1, c1);
  f4v a4[4] = {};
  {
    s8v af[2][4];
    #pragma unroll
    for (int ks = 0; ks < 2; ++ks)
      #pragma unroll
      for (int fm = 0; fm < 4; ++fm)
        af[ks][fm] = *(const s8v*)(act + abase + fm * 16 * 72 + ks * 32);
    s8v b0 = *(const s8v*)(Wb + lr * 72 + lk * 8);
    s8v b1 = *(const s8v*)(Wb + lr * 72 + 32 + lk * 8);
    #pragma unroll
    for (int fm = 0; fm < 4; ++fm) {
      a4[fm] = __builtin_amdgcn_mfma_f32_16x16x32_bf16(af[0][fm], b0, a4[fm], 0, 0, 0);
      a4[fm] = __builtin_amdgcn_mfma_f32_16x16x32_bf16(af[1][fm], b1, a4[fm], 0, 0, 0);
    }
  }
  if (lr < 5) {
    const float b5 = b15[lr];
    #pragma unroll
    for (int fm = 0; fm < 4; ++fm)
      #pragma unroll
      for (int j = 0; j < 4; ++j) {
        const int row = w * 64 + fm * 16 + lk * 4 + j;
        float v = a4[fm][j] + b5;
        v = (v - m2) * s2 + c2;
        v = fmaxf(v, 0.f);
        h5b[(size_t)row * 13376 + (size_t)i * 5 + lr] = f2b(v);
      }
  }
}

extern "C" void kernel_launch(void* const* d_in, const int* in_sizes, int n_in,
                              void* d_out, int out_size, void* d_ws, size_t ws_size,
                              hipStream_t stream)
{
  const float* x    = (const float*)d_in[0];
  const float* W1   = (const float*)d_in[1];
  const float* b1   = (const float*)d_in[2];
  const float* Wmid = (const float*)d_in[3];
  const float* bmid = (const float*)d_in[4];
  const float* bng  = (const float*)d_in[5];
  const float* bnb  = (const float*)d_in[6];
  const float* bnrm = (const float*)d_in[7];
  const float* bnrv = (const float*)d_in[8];
  const float* Wlin = (const float*)d_in[9];
  const float* blin = (const float*)d_in[10];
  const float* W13  = (const float*)d_in[11];
  const float* b13  = (const float*)d_in[12];
  const float* W14  = (const float*)d_in[13];
  const float* b14  = (const float*)d_in[14];
  const float* W15  = (const float*)d_in[15];
  const float* b15  = (const float*)d_in[16];
  const float* bn3g = (const float*)d_in[17];
  const float* bn3b = (const float*)d_in[18];
  const float* bn3rm= (const float*)d_in[19];
  const float* bn3rv= (const float*)d_in[20];
  const float* W16  = (const float*)d_in[21];
  const float* b16  = (const float*)d_in[22];
  const float* W17  = (const float*)d_in[23];
  const float* b17  = (const float*)d_in[24];
  const float* W18  = (const float*)d_in[25];
  const float* b18  = (const float*)d_in[26];

  const int R = 2666;
  char* p = (char*)d_ws;
  unsigned short* xg  = (unsigned short*)p; p += (size_t)256 * 16384 * 2;
  unsigned short* hA  = (unsigned short*)p; p += (size_t)256 * 2688 * 2;
  unsigned short* hB  = (unsigned short*)p; p += (size_t)256 * 2688 * 2;
  float*          dR  = (float*)p;          p += (size_t)256 * 2688 * 4;
  unsigned short* h5b = (unsigned short*)p; p += (size_t)256 * 13376 * 2;
  unsigned short* h6b = (unsigned short*)p; p += (size_t)256 * 768 * 2;
  unsigned short* h7b = (unsigned short*)p; p += (size_t)256 * 768 * 2;
  unsigned short* envb= (unsigned short*)p; p += (size_t)256 * 72 * 2;
  unsigned short* htr = (unsigned short*)p; p += (size_t)2666 * 256 * 2;
  unsigned short* Pb  = (unsigned short*)p; // bf16 partials, <= 18.4 MB

  dim3 TB(256);

  prep_k<<<dim3(16457), TB, 0, stream>>>(x, xg, envb, h5b);

  // Cooperative L1 + 11 mids: grid 504 (42 x 12), 2 blocks/CU.
  hipError_t cerr;
  {
    void* args[] = {
      (void*)&xg, (void*)&W1, (void*)&b1, (void*)&Wmid, (void*)&bmid,
      (void*)&bng, (void*)&bnb, (void*)&bnrm, (void*)&bnrv,
      (void*)&dR, (void*)&hA, (void*)&hB, (void*)&htr, (void*)&Pb
    };
    cerr = hipLaunchCooperativeKernel((const void*)coop_chain, dim3(504), TB,
                                      args, 0, stream);
  }
  if (cerr != hipSuccess) {
    // Fallback: proven r8-style separate launches (L1 KS=8, mids KS=14).
    gemm_bk64<<<dim3(42 * 8), TB, 0, stream>>>(xg, 16384, W1, 16384, Pb, 42, R, 16384, 2048, 8);
    reduce_bk64<true, false, true, false, false><<<dim3(42 * 4), TB, 0, stream>>>(
        Pb, 8, 42, R, b1, bng, bnb, bnrm, bnrv, dR, 2688, hA, 2688, nullptr, nullptr);
    unsigned short* cur = hA; unsigned short* nxt = hB;
    for (int k = 0; k < 11; ++k) {
      const float* bw = Wmid + (size_t)k * R * R;
      const float* bs = bmid + (size_t)k * R;
      const int L = k + 1;
      gemm_bk64<<<dim3(42 * 14), TB, 0, stream>>>(cur, 2688, bw, R, Pb, 42, R, R, 192, 14);
      if (k == 10)
        reduce_bk64<true, false, false, true, false><<<dim3(42 * 4), TB, 0, stream>>>(
            Pb, 14, 42, R, bs, bng + (size_t)L * R, bnb + (size_t)L * R,
            bnrm + (size_t)L * R, bnrv + (size_t)L * R,
            nullptr, 0, nullptr, 2688, htr, nullptr);
      else if ((k & 1) == 0)
        reduce_bk64<true, false, false, false, false><<<dim3(42 * 4), TB, 0, stream>>>(
            Pb, 14, 42, R, bs, bng + (size_t)L * R, bnb + (size_t)L * R,
            bnrm + (size_t)L * R, bnrv + (size_t)L * R,
            nullptr, 0, nxt, 2688, nullptr, nullptr);
      else
        reduce_bk64<true, true, true, false, false><<<dim3(42 * 4), TB, 0, stream>>>(
            Pb, 14, 42, R, bs, bng + (size_t)L * R, bnb + (size_t)L * R,
            bnrm + (size_t)L * R, bnrv + (size_t)L * R,
            dR, 2688, nxt, 2688, nullptr, nullptr);
      unsigned short* tmp = cur; cur = nxt; nxt = tmp;
    }
  }

  // Fused d3 -> W13 -> W14 -> W15 chain
  fused_head<<<dim3(2666), TB, 0, stream>>>(
      envb, htr, Wlin, blin, W13, b13, W14, b14, W15, b15,
      bn3g, bn3b, bn3rm, bn3rv, h5b);

  // W16: K=13330, NPAIR=12, KS=15, kchunk=896 (15*896=13440 >= 13330; ky=14:
  // 12544..13330, nfull=12, rem=18 -> slab 13312..13376 = lda). Grid 180.
  gemm_bk64<<<dim3(12 * 15), TB, 0, stream>>>(h5b, 13376, W16, 13330, Pb, 12, 750, 13330, 896, 15);
  reduce_bk64<false, false, false, false, false><<<dim3(12 * 4), TB, 0, stream>>>(
      Pb, 15, 12, 750, b16, nullptr, nullptr, nullptr, nullptr,
      nullptr, 0, h6b, 768, nullptr, nullptr);

  // W17: K=750, KS=6, kchunk=128 (6*128=768 >= 750; ky=5: 640..750, nfull=1,
  // rem=46 -> slab 704..768 = lda). Grid 72.
  gemm_bk64<<<dim3(12 * 6), TB, 0, stream>>>(h6b, 768, W17, 750, Pb, 12, 750, 750, 128, 6);
  reduce_bk64<false, false, false, false, false><<<dim3(12 * 4), TB, 0, stream>>>(
      Pb, 6, 12, 750, b17, nullptr, nullptr, nullptr, nullptr,
      nullptr, 0, h7b, 768, nullptr, nullptr);

  // W18 -> f32 d_out
  gemm_bk64<<<dim3(12 * 6), TB, 0, stream>>>(h7b, 768, W18, 750, Pb, 12, 750, 750, 128, 6);
  reduce_bk64<false, false, false, false, true><<<dim3(12 * 4), TB, 0, stream>>>(
      Pb, 6, 12, 750, b18, nullptr, nullptr, nullptr, nullptr,
      nullptr, 0, nullptr, 768, nullptr, (float*)d_out);
}

// Round 14
// 818.585 us; speedup vs baseline: 2.5942x; 2.5942x over previous
//
#include <hip/hip_runtime.h>

#define EPS 1e-5f

typedef __attribute__((ext_vector_type(8))) short s8v;   // 8 x bf16 bits
typedef __attribute__((ext_vector_type(4))) float f4v;   // MFMA accumulator

__device__ __forceinline__ unsigned short f2b(float x) {
  unsigned int u = __float_as_uint(x);
  u += 0x7FFFu + ((u >> 16) & 1u);
  return (unsigned short)(u >> 16);
}
__device__ __forceinline__ float b2f(unsigned short b) {
  return __uint_as_float(((unsigned int)b) << 16);
}

// ===========================================================================
// No-split-K GEMM with fused epilogue (mids, W17, W18). ONE dispatch/layer.
//   A: 256 x K bf16 (lda: slab [kb,kb+64) always fits, pads zero)
//   B: N x K f32. Tile 64x64, grid 4*NT blocks (mr=bid&3, nt=bid>>2).
//   4 waves; wave w owns rows m0 + w*16 .. +16. 8 MFMA/wave/step, f32 acc
//   across the FULL K (no partial round-trip, no reduce dispatch).
//   Epilogue: bias [+BN] +relu [+residual dR] [dR write] [htr transpose
//   (WRT: no Cb write)] -> bf16 Cb (pad cols zeroed) or f32 Cf.
// ===========================================================================
template<bool BN, bool RES, bool WRD, bool WRT, bool F32OUT>
__global__ __launch_bounds__(256)
void gemm_direct(const unsigned short* __restrict__ A, int lda,
                 const float* __restrict__ B, int ldb,
                 const float* __restrict__ bias,
                 const float* __restrict__ g, const float* __restrict__ bb,
                 const float* __restrict__ rm, const float* __restrict__ rv,
                 float* __restrict__ dR, int lddr,
                 unsigned short* __restrict__ Cb, int ldc,
                 unsigned short* __restrict__ htr, float* __restrict__ Cf,
                 int N, int K)
{
  __shared__ unsigned short As[64 * 72];
  __shared__ unsigned short Bs[64 * 72];
  const int bid = (int)blockIdx.x;
  const int mr = bid & 3, nt = bid >> 2;
  const int m0 = mr << 6, n0 = nt << 6;
  const int t = threadIdx.x, lane = t & 63, w = t >> 6;
  const int lr = lane & 15, lk = lane >> 4;
  const int ar = t >> 2, ac = t & 3;     // A: row ar (0..63), 16-col half ac
  const int br = t >> 2, bq = t & 3;     // B: row br (0..63), 16-col quad bq

  const int nfull = K >> 6;
  const int rem = K & 63;

  f4v acc[4] = {};
  float4 b_cur[4], b_nxt[4];

  auto loadB = [&](float4* dst, int kb) {
    const int row = n0 + br;
    if (row < N) {
      #pragma unroll
      for (int i = 0; i < 4; ++i)
        dst[i] = *(const float4*)(B + (size_t)row * ldb + kb + bq * 16 + i * 4);
    } else {
      #pragma unroll
      for (int i = 0; i < 4; ++i) { dst[i].x = dst[i].y = dst[i].z = dst[i].w = 0.f; }
    }
  };
  auto stageA = [&](int kb) {
    const s8v v0 = *(const s8v*)(A + (size_t)(m0 + ar) * lda + kb + ac * 16);
    const s8v v1 = *(const s8v*)(A + (size_t)(m0 + ar) * lda + kb + ac * 16 + 8);
    *(s8v*)(As + ar * 72 + ac * 16) = v0;
    *(s8v*)(As + ar * 72 + ac * 16 + 8) = v1;
  };
  auto stageB = [&](const float4* bv) {
    s8v p0, p1;
    p0[0] = (short)f2b(bv[0].x); p0[1] = (short)f2b(bv[0].y);
    p0[2] = (short)f2b(bv[0].z); p0[3] = (short)f2b(bv[0].w);
    p0[4] = (short)f2b(bv[1].x); p0[5] = (short)f2b(bv[1].y);
    p0[6] = (short)f2b(bv[1].z); p0[7] = (short)f2b(bv[1].w);
    p1[0] = (short)f2b(bv[2].x); p1[1] = (short)f2b(bv[2].y);
    p1[2] = (short)f2b(bv[2].z); p1[3] = (short)f2b(bv[2].w);
    p1[4] = (short)f2b(bv[3].x); p1[5] = (short)f2b(bv[3].y);
    p1[6] = (short)f2b(bv[3].z); p1[7] = (short)f2b(bv[3].w);
    *(s8v*)(Bs + br * 72 + bq * 16) = p0;
    *(s8v*)(Bs + br * 72 + bq * 16 + 8) = p1;
  };
  auto domfma = [&]() {
    #pragma unroll
    for (int ks = 0; ks < 2; ++ks) {
      s8v af = *(const s8v*)(As + (w * 16 + lr) * 72 + ks * 32 + lk * 8);
      #pragma unroll
      for (int fn = 0; fn < 4; ++fn) {
        s8v bf = *(const s8v*)(Bs + (fn * 16 + lr) * 72 + ks * 32 + lk * 8);
        acc[fn] = __builtin_amdgcn_mfma_f32_16x16x32_bf16(af, bf, acc[fn], 0, 0, 0);
      }
    }
  };

  int kb = 0;
  if (nfull > 0) {
    loadB(b_cur, 0);
    for (int s = 0; s < nfull; ++s) {
      stageA(kb);
      stageB(b_cur);
      __syncthreads();
      const bool more = (s + 1 < nfull);
      if (more) loadB(b_nxt, kb + 64);
      domfma();
      __syncthreads();
      if (more) {
        #pragma unroll
        for (int i = 0; i < 4; ++i) b_cur[i] = b_nxt[i];
        kb += 64;
      }
    }
    kb += 64;
  }
  if (rem) {
    stageA(kb);                      // slab fits lda, pads zero
    {
      const int row = n0 + br;
      #pragma unroll
      for (int i = 0; i < 4; ++i) {
        float e[4];
        #pragma unroll
        for (int v = 0; v < 4; ++v) {
          const int c = kb + bq * 16 + i * 4 + v;
          e[v] = (row < N && c < K) ? B[(size_t)row * ldb + c] : 0.f;
        }
        b_cur[i].x = e[0]; b_cur[i].y = e[1]; b_cur[i].z = e[2]; b_cur[i].w = e[3];
      }
    }
    stageB(b_cur);
    __syncthreads();
    domfma();
    __syncthreads();
  }

  // Fused epilogue
  #pragma unroll
  for (int fn = 0; fn < 4; ++fn) {
    const int col = n0 + fn * 16 + lr;
    const bool cin = (col < N);
    #pragma unroll
    for (int j = 0; j < 4; ++j) {
      const int row = m0 + w * 16 + lk * 4 + j;
      float v = 0.f;
      if (cin) {
        v = acc[fn][j] + bias[col];
        if (BN) { const float s = g[col] * rsqrtf(rv[col] + EPS); v = (v - rm[col]) * s + bb[col]; }
        v = fmaxf(v, 0.f);
        if (RES) v += dR[(size_t)row * lddr + col];
        if (WRD) dR[(size_t)row * lddr + col] = v;
      }
      if (WRT) {
        if (cin) htr[(size_t)col * 256 + row] = f2b(v);
      } else if (F32OUT) {
        if (cin) Cf[(size_t)row * N + col] = v;
      } else {
        Cb[(size_t)row * ldc + col] = f2b(v);   // pad cols get 0
      }
    }
  }
}

// ===========================================================================
// Split-K GEMM (L1, W16 only) + reduce — proven r8/r13 structure.
// HOST INVARIANTS: kchunk % 64 == 0; KS*kchunk >= K; staged slabs fit lda.
// ===========================================================================
__global__ __launch_bounds__(256)
void gemm_bk64(const unsigned short* __restrict__ A, int lda,
               const float* __restrict__ B, int ldb,
               unsigned short* __restrict__ Pb,
               int NPAIR, int N, int K, int kchunk, int KS)
{
  __shared__ unsigned short As[256 * 72];
  __shared__ unsigned short Bs[64 * 72];
  const int bid = (int)blockIdx.x;
  const int ky = bid % KS, ntp = bid / KS;
  const int n0 = ntp << 6;
  const int t = threadIdx.x, lane = t & 63, w = t >> 6;
  const int lr = lane & 15, lk = lane >> 4;

  const int kstart = ky * kchunk;
  const int kend = min(K, kstart + kchunk);
  const int len = kend - kstart;
  const int nfull = (len > 0) ? (len >> 6) : 0;
  const int rem = (len > 0) ? (len & 63) : 0;

  const int ar = t >> 2, ac = t & 3;
  const int br = t >> 2, bq = t & 3;

  f4v acc[4][4] = {};
  float4 b_cur[4], b_nxt[4];

  auto loadB = [&](float4* dst, int kb) {
    const int row = n0 + br;
    if (row < N) {
      #pragma unroll
      for (int i = 0; i < 4; ++i)
        dst[i] = *(const float4*)(B + (size_t)row * ldb + kb + bq * 16 + i * 4);
    } else {
      #pragma unroll
      for (int i = 0; i < 4; ++i) { dst[i].x = dst[i].y = dst[i].z = dst[i].w = 0.f; }
    }
  };
  auto stageA = [&](int kb) {
    #pragma unroll
    for (int p = 0; p < 4; ++p) {
      const int row = ar + p * 64;
      const s8v v0 = *(const s8v*)(A + (size_t)row * lda + kb + ac * 16);
      const s8v v1 = *(const s8v*)(A + (size_t)row * lda + kb + ac * 16 + 8);
      *(s8v*)(As + row * 72 + ac * 16) = v0;
      *(s8v*)(As + row * 72 + ac * 16 + 8) = v1;
    }
  };
  auto stageB = [&](const float4* bv) {
    s8v p0, p1;
    p0[0] = (short)f2b(bv[0].x); p0[1] = (short)f2b(bv[0].y);
    p0[2] = (short)f2b(bv[0].z); p0[3] = (short)f2b(bv[0].w);
    p0[4] = (short)f2b(bv[1].x); p0[5] = (short)f2b(bv[1].y);
    p0[6] = (short)f2b(bv[1].z); p0[7] = (short)f2b(bv[1].w);
    p1[0] = (short)f2b(bv[2].x); p1[1] = (short)f2b(bv[2].y);
    p1[2] = (short)f2b(bv[2].z); p1[3] = (short)f2b(bv[2].w);
    p1[4] = (short)f2b(bv[3].x); p1[5] = (short)f2b(bv[3].y);
    p1[6] = (short)f2b(bv[3].z); p1[7] = (short)f2b(bv[3].w);
    *(s8v*)(Bs + br * 72 + bq * 16) = p0;
    *(s8v*)(Bs + br * 72 + bq * 16 + 8) = p1;
  };
  auto domfma = [&]() {
    #pragma unroll
    for (int ks = 0; ks < 2; ++ks) {
      s8v af[4], bf[4];
      #pragma unroll
      for (int fm = 0; fm < 4; ++fm)
        af[fm] = *(const s8v*)(As + (w * 64 + fm * 16 + lr) * 72 + ks * 32 + lk * 8);
      #pragma unroll
      for (int fn = 0; fn < 4; ++fn)
        bf[fn] = *(const s8v*)(Bs + (fn * 16 + lr) * 72 + ks * 32 + lk * 8);
      #pragma unroll
      for (int fm = 0; fm < 4; ++fm)
        #pragma unroll
        for (int fn = 0; fn < 4; ++fn)
          acc[fm][fn] = __builtin_amdgcn_mfma_f32_16x16x32_bf16(af[fm], bf[fn], acc[fm][fn], 0, 0, 0);
    }
  };

  int kb = kstart;
  if (nfull > 0) {
    loadB(b_cur, kb);
    for (int s = 0; s < nfull; ++s) {
      stageA(kb);
      stageB(b_cur);
      __syncthreads();
      const bool more = (s + 1 < nfull);
      if (more) loadB(b_nxt, kb + 64);
      domfma();
      __syncthreads();
      if (more) {
        #pragma unroll
        for (int i = 0; i < 4; ++i) b_cur[i] = b_nxt[i];
        kb += 64;
      }
    }
    kb += 64;
  }
  if (rem) {
    stageA(kb);
    {
      const int row = n0 + br;
      #pragma unroll
      for (int i = 0; i < 4; ++i) {
        float e[4];
        #pragma unroll
        for (int v = 0; v < 4; ++v) {
          const int c = kb + bq * 16 + i * 4 + v;
          e[v] = (row < N && c < kend) ? B[(size_t)row * ldb + c] : 0.f;
        }
        b_cur[i].x = e[0]; b_cur[i].y = e[1]; b_cur[i].z = e[2]; b_cur[i].w = e[3];
      }
    }
    stageB(b_cur);
    __syncthreads();
    domfma();
    __syncthreads();
  }

  unsigned short* Pt = Pb + ((size_t)ky * NPAIR + ntp) * 16384;
  #pragma unroll
  for (int fm = 0; fm < 4; ++fm)
    #pragma unroll
    for (int fn = 0; fn < 4; ++fn) {
      const int col = fn * 16 + lr;
      #pragma unroll
      for (int j = 0; j < 4; ++j) {
        const int row = w * 64 + fm * 16 + lk * 4 + j;
        Pt[row * 64 + col] = f2b(acc[fm][fn][j]);
      }
    }
}

template<bool BN, bool WRD>
__global__ __launch_bounds__(256)
void reduce_bk64(const unsigned short* __restrict__ Pb, int KS, int NPAIR, int N,
                 const float* __restrict__ bias,
                 const float* __restrict__ g, const float* __restrict__ bb,
                 const float* __restrict__ rm, const float* __restrict__ rv,
                 float* __restrict__ dR, int lddr,
                 unsigned short* __restrict__ Cb, int ldc)
{
  const int bid = (int)blockIdx.x;
  const int ntp = bid >> 2, qr = bid & 3;
  const int t = threadIdx.x;
  const int row = qr * 64 + (t >> 2);
  const int c0 = (t & 3) * 16;
  const int n0 = ntp << 6;

  float vv[16];
  #pragma unroll
  for (int e = 0; e < 16; ++e) vv[e] = 0.f;
  const unsigned short* base = Pb + (size_t)ntp * 16384 + row * 64 + c0;
  for (int ky = 0; ky < KS; ++ky) {
    const s8v pa  = *(const s8v*)(base + (size_t)ky * NPAIR * 16384);
    const s8v pb2 = *(const s8v*)(base + (size_t)ky * NPAIR * 16384 + 8);
    #pragma unroll
    for (int e = 0; e < 8; ++e) vv[e]     += b2f((unsigned short)pa[e]);
    #pragma unroll
    for (int e = 0; e < 8; ++e) vv[8 + e] += b2f((unsigned short)pb2[e]);
  }
  unsigned short outp[16];
  #pragma unroll
  for (int e = 0; e < 16; ++e) {
    const int col = n0 + c0 + e;
    float v = 0.f;
    if (col < N) {
      v = vv[e] + bias[col];
      if (BN) { const float s = g[col] * rsqrtf(rv[col] + EPS); v = (v - rm[col]) * s + bb[col]; }
      v = fmaxf(v, 0.f);
      if (WRD) dR[(size_t)row * lddr + col] = v;
    }
    outp[e] = f2b(v);
  }
  *(s8v*)(Cb + (size_t)row * ldc + n0 + c0) = *(const s8v*)(outp);
  *(s8v*)(Cb + (size_t)row * ldc + n0 + c0 + 8) = *(const s8v*)(outp + 8);
}

// ---------------------------------------------------------------------------
// Prep: pack x-geno to bf16, pack env rows, zero h5b pads (stride 13376).
// ---------------------------------------------------------------------------
__global__ __launch_bounds__(256)
void prep_k(const float* __restrict__ x, unsigned short* __restrict__ xg,
            unsigned short* __restrict__ envb, unsigned short* __restrict__ h5b)
{
  const int bid = (int)blockIdx.x, t = threadIdx.x;
  if (bid < 16384) {
    const int idx = bid * 256 + t;
    const int r = idx >> 14, c = idx & 16383;
    xg[idx] = f2b(x[(size_t)r * 16437 + c]);
  } else if (bid < 16456) {
    const int idx = (bid - 16384) * 256 + t;
    const int b = idx / 72, c = idx % 72;
    envb[idx] = (c < 53) ? f2b(x[(size_t)b * 16437 + 16384 + c]) : (unsigned short)0;
  } else {
    for (int z = t; z < 256 * 46; z += 256) {
      const int b = z / 46, j = z % 46;
      h5b[(size_t)b * 13376 + 13330 + j] = 0;
    }
  }
}

// ---------------------------------------------------------------------------
// Fused head: per unit i, 4 chained 256x64x64 GEMMs in LDS/regs (unchanged).
// ---------------------------------------------------------------------------
__global__ __launch_bounds__(256, 2)
void fused_head(const unsigned short* __restrict__ envb,
                const unsigned short* __restrict__ htr,
                const float* __restrict__ Wlin, const float* __restrict__ blin,
                const float* __restrict__ W13, const float* __restrict__ b13,
                const float* __restrict__ W14, const float* __restrict__ b14,
                const float* __restrict__ W15, const float* __restrict__ b15,
                const float* __restrict__ bn3g, const float* __restrict__ bn3b,
                const float* __restrict__ bn3rm, const float* __restrict__ bn3rv,
                unsigned short* __restrict__ h5b)
{
  __shared__ unsigned short act[256 * 72];
  __shared__ unsigned short Wl[64 * 72];
  __shared__ unsigned short Wa[64 * 72];
  __shared__ unsigned short Wb[16 * 72];
  const int i = (int)blockIdx.x;
  const int t = threadIdx.x, lane = t & 63, w = t >> 6;
  const int lr = lane & 15, lk = lane >> 4;
  const int R = 2666;

  #pragma unroll
  for (int c8 = 0; c8 < 9; ++c8)
    *(s8v*)(act + t * 72 + c8 * 8) = *(const s8v*)(envb + t * 72 + c8 * 8);
  act[t * 72 + 53] = htr[(size_t)i * 256 + t];

  const float* wli = Wlin + (size_t)i * 2916;
  for (int idx = t; idx < 64 * 72; idx += 256) {
    const int r = idx / 72, f = idx % 72;
    Wl[idx] = (r < 54 && f < 54) ? f2b(wli[r * 54 + f]) : (unsigned short)0;
    Wa[idx] = (r < 54 && f < 54) ? f2b(W13[r * 54 + f]) : (unsigned short)0;
  }
  for (int idx = t; idx < 16 * 72; idx += 256) {
    const int r = idx / 72, f = idx % 72;
    Wb[idx] = (r < 5 && f < 54) ? f2b(W15[r * 54 + f]) : (unsigned short)0;
  }
  const float s0 = bn3g[i] * rsqrtf(bn3rv[i] + EPS), m0 = bn3rm[i], c0 = bn3b[i];
  const float s1 = bn3g[R+i] * rsqrtf(bn3rv[R+i] + EPS), m1 = bn3rm[R+i], c1 = bn3b[R+i];
  const float s2 = bn3g[2*R+i] * rsqrtf(bn3rv[2*R+i] + EPS), m2 = bn3rm[2*R+i], c2 = bn3b[2*R+i];
  __syncthreads();

  const int abase = (w * 64 + lr) * 72 + lk * 8;
  f4v acc[4][4];

  auto zacc = [&]() {
    #pragma unroll
    for (int a = 0; a < 4; ++a)
      #pragma unroll
      for (int b = 0; b < 4; ++b) acc[a][b] = f4v{0.f, 0.f, 0.f, 0.f};
  };
  auto gemm4 = [&](const unsigned short* B) {
    s8v af[2][4];
    #pragma unroll
    for (int ks = 0; ks < 2; ++ks)
      #pragma unroll
      for (int fm = 0; fm < 4; ++fm)
        af[ks][fm] = *(const s8v*)(act + abase + fm * 16 * 72 + ks * 32);
    #pragma unroll
    for (int fn = 0; fn < 4; ++fn) {
      s8v b0 = *(const s8v*)(B + (fn * 16 + lr) * 72 + lk * 8);
      s8v b1 = *(const s8v*)(B + (fn * 16 + lr) * 72 + 32 + lk * 8);
      #pragma unroll
      for (int fm = 0; fm < 4; ++fm) {
        acc[fm][fn] = __builtin_amdgcn_mfma_f32_16x16x32_bf16(af[0][fm], b0, acc[fm][fn], 0, 0, 0);
        acc[fm][fn] = __builtin_amdgcn_mfma_f32_16x16x32_bf16(af[1][fm], b1, acc[fm][fn], 0, 0, 0);
      }
    }
  };
  auto epi_bn = [&](const float* bias, float s, float m, float c) {
    #pragma unroll
    for (int fn = 0; fn < 4; ++fn) {
      const int o = fn * 16 + lr;
      const float bo = (o < 54) ? bias[o] : 0.f;
      #pragma unroll
      for (int fm = 0; fm < 4; ++fm)
        #pragma unroll
        for (int j = 0; j < 4; ++j) {
          const int row = w * 64 + fm * 16 + lk * 4 + j;
          float v = acc[fm][fn][j] + bo;
          v = (v - m) * s + c;
          v = fmaxf(v, 0.f);
          act[row * 72 + o] = (o < 54) ? f2b(v) : (unsigned short)0;
        }
    }
  };

  zacc(); gemm4(Wl);
  #pragma unroll
  for (int fn = 0; fn < 4; ++fn) {
    const int o = fn * 16 + lr;
    const float bl = (o < 54) ? blin[(size_t)i * 54 + o] : 0.f;
    #pragma unroll
    for (int fm = 0; fm < 4; ++fm)
      #pragma unroll
      for (int j = 0; j < 4; ++j) {
        const int row = w * 64 + fm * 16 + lk * 4 + j;
        float v = acc[fm][fn][j] + bl;
        act[row * 72 + o] = (o < 54) ? f2b(v) : (unsigned short)0;
      }
  }
  __syncthreads();
  for (int idx = t; idx < 64 * 72; idx += 256) {
    const int r = idx / 72, f = idx % 72;
    Wl[idx] = (r < 54 && f < 54) ? f2b(W14[r * 54 + f]) : (unsigned short)0;
  }
  zacc(); gemm4(Wa); epi_bn(b13, s0, m0, c0);
  __syncthreads();
  zacc(); gemm4(Wl); epi_bn(b14, s1, m1, c1);
  f4v a4[4] = {};
  {
    s8v af[2][4];
    #pragma unroll
    for (int ks = 0; ks < 2; ++ks)
      #pragma unroll
      for (int fm = 0; fm < 4; ++fm)
        af[ks][fm] = *(const s8v*)(act + abase + fm * 16 * 72 + ks * 32);
    s8v b0 = *(const s8v*)(Wb + lr * 72 + lk * 8);
    s8v b1 = *(const s8v*)(Wb + lr * 72 + 32 + lk * 8);
    #pragma unroll
    for (int fm = 0; fm < 4; ++fm) {
      a4[fm] = __builtin_amdgcn_mfma_f32_16x16x32_bf16(af[0][fm], b0, a4[fm], 0, 0, 0);
      a4[fm] = __builtin_amdgcn_mfma_f32_16x16x32_bf16(af[1][fm], b1, a4[fm], 0, 0, 0);
    }
  }
  if (lr < 5) {
    const float b5 = b15[lr];
    #pragma unroll
    for (int fm = 0; fm < 4; ++fm)
      #pragma unroll
      for (int j = 0; j < 4; ++j) {
        const int row = w * 64 + fm * 16 + lk * 4 + j;
        float v = a4[fm][j] + b5;
        v = (v - m2) * s2 + c2;
        v = fmaxf(v, 0.f);
        h5b[(size_t)row * 13376 + (size_t)i * 5 + lr] = f2b(v);
      }
  }
}

extern "C" void kernel_launch(void* const* d_in, const int* in_sizes, int n_in,
                              void* d_out, int out_size, void* d_ws, size_t ws_size,
                              hipStream_t stream)
{
  const float* x    = (const float*)d_in[0];
  const float* W1   = (const float*)d_in[1];
  const float* b1   = (const float*)d_in[2];
  const float* Wmid = (const float*)d_in[3];
  const float* bmid = (const float*)d_in[4];
  const float* bng  = (const float*)d_in[5];
  const float* bnb  = (const float*)d_in[6];
  const float* bnrm = (const float*)d_in[7];
  const float* bnrv = (const float*)d_in[8];
  const float* Wlin = (const float*)d_in[9];
  const float* blin = (const float*)d_in[10];
  const float* W13  = (const float*)d_in[11];
  const float* b13  = (const float*)d_in[12];
  const float* W14  = (const float*)d_in[13];
  const float* b14  = (const float*)d_in[14];
  const float* W15  = (const float*)d_in[15];
  const float* b15  = (const float*)d_in[16];
  const float* bn3g = (const float*)d_in[17];
  const float* bn3b = (const float*)d_in[18];
  const float* bn3rm= (const float*)d_in[19];
  const float* bn3rv= (const float*)d_in[20];
  const float* W16  = (const float*)d_in[21];
  const float* b16  = (const float*)d_in[22];
  const float* W17  = (const float*)d_in[23];
  const float* b17  = (const float*)d_in[24];
  const float* W18  = (const float*)d_in[25];
  const float* b18  = (const float*)d_in[26];

  const int R = 2666;
  char* p = (char*)d_ws;
  unsigned short* xg  = (unsigned short*)p; p += (size_t)256 * 16384 * 2;
  unsigned short* hA  = (unsigned short*)p; p += (size_t)256 * 2688 * 2;
  unsigned short* hB  = (unsigned short*)p; p += (size_t)256 * 2688 * 2;
  float*          dR  = (float*)p;          p += (size_t)256 * 2688 * 4;
  unsigned short* h5b = (unsigned short*)p; p += (size_t)256 * 13376 * 2;
  unsigned short* h6b = (unsigned short*)p; p += (size_t)256 * 768 * 2;
  unsigned short* h7b = (unsigned short*)p; p += (size_t)256 * 768 * 2;
  unsigned short* envb= (unsigned short*)p; p += (size_t)256 * 72 * 2;
  unsigned short* htr = (unsigned short*)p; p += (size_t)2666 * 256 * 2;
  unsigned short* Pb  = (unsigned short*)p; // bf16 partials (L1/W16), <= 11 MB

  dim3 TB(256);

  prep_k<<<dim3(16457), TB, 0, stream>>>(x, xg, envb, h5b);

  // L1 (split-K): K=16384, NPAIR=42, KS=8, kchunk=2048. Grid 336. + reduce.
  gemm_bk64<<<dim3(42 * 8), TB, 0, stream>>>(xg, 16384, W1, 16384, Pb, 42, R, 16384, 2048, 8);
  reduce_bk64<true, true><<<dim3(42 * 4), TB, 0, stream>>>(
      Pb, 8, 42, R, b1, bng, bnb, bnrm, bnrv, dR, 2688, hA, 2688);

  // 11 mids: ONE no-split-K dispatch each (fused epilogue). Grid 168.
  unsigned short* cur = hA; unsigned short* nxt = hB;
  for (int k = 0; k < 11; ++k) {
    const float* bw = Wmid + (size_t)k * R * R;
    const float* bs = bmid + (size_t)k * R;
    const int L = k + 1;
    if (k == 10)
      gemm_direct<true, false, false, true, false><<<dim3(4 * 42), TB, 0, stream>>>(
          cur, 2688, bw, R, bs, bng + (size_t)L * R, bnb + (size_t)L * R,
          bnrm + (size_t)L * R, bnrv + (size_t)L * R,
          dR, 2688, nxt, 2688, htr, nullptr, R, R);
    else if ((k & 1) == 0)
      gemm_direct<true, false, false, false, false><<<dim3(4 * 42), TB, 0, stream>>>(
          cur, 2688, bw, R, bs, bng + (size_t)L * R, bnb + (size_t)L * R,
          bnrm + (size_t)L * R, bnrv + (size_t)L * R,
          dR, 2688, nxt, 2688, nullptr, nullptr, R, R);
    else
      gemm_direct<true, true, true, false, false><<<dim3(4 * 42), TB, 0, stream>>>(
          cur, 2688, bw, R, bs, bng + (size_t)L * R, bnb + (size_t)L * R,
          bnrm + (size_t)L * R, bnrv + (size_t)L * R,
          dR, 2688, nxt, 2688, nullptr, nullptr, R, R);
    unsigned short* tmp = cur; cur = nxt; nxt = tmp;
  }

  // Fused d3 -> W13 -> W14 -> W15 chain
  fused_head<<<dim3(2666), TB, 0, stream>>>(
      envb, htr, Wlin, blin, W13, b13, W14, b14, W15, b15,
      bn3g, bn3b, bn3rm, bn3rv, h5b);

  // W16 (split-K): K=13330, NPAIR=12, KS=15, kchunk=896 (15*896 >= 13330;
  // ky=14: rem=18, slab 13312..13376 = lda). Grid 180. + reduce -> h6b.
  gemm_bk64<<<dim3(12 * 15), TB, 0, stream>>>(h5b, 13376, W16, 13330, Pb, 12, 750, 13330, 896, 15);
  reduce_bk64<false, false><<<dim3(12 * 4), TB, 0, stream>>>(
      Pb, 15, 12, 750, b16, nullptr, nullptr, nullptr, nullptr, nullptr, 0, h6b, 768);

  // W17: no-split direct (K=750, lda 768: nfull=11, rem=46, slab 704..768 ok).
  gemm_direct<false, false, false, false, false><<<dim3(4 * 12), TB, 0, stream>>>(
      h6b, 768, W17, 750, b17, nullptr, nullptr, nullptr, nullptr,
      nullptr, 0, h7b, 768, nullptr, nullptr, 750, 750);

  // W18: no-split direct -> f32 d_out.
  gemm_direct<false, false, false, false, true><<<dim3(4 * 12), TB, 0, stream>>>(
      h7b, 768, W18, 750, b18, nullptr, nullptr, nullptr, nullptr,
      nullptr, 0, nullptr, 768, nullptr, (float*)d_out, 750, 750);
}

// Round 15
// 597.610 us; speedup vs baseline: 3.5535x; 1.3698x over previous
//
#include <hip/hip_runtime.h>

#define EPS 1e-5f

typedef __attribute__((ext_vector_type(8))) short s8v;   // 8 x bf16 bits
typedef __attribute__((ext_vector_type(4))) float f4v;   // MFMA accumulator

__device__ __forceinline__ unsigned short f2b(float x) {
  unsigned int u = __float_as_uint(x);
  u += 0x7FFFu + ((u >> 16) & 1u);
  return (unsigned short)(u >> 16);
}
__device__ __forceinline__ float b2f(unsigned short b) {
  return __uint_as_float(((unsigned int)b) << 16);
}

// ===========================================================================
// Split-K GEMM, BK=64, tile 256x64, bf16 partials (r8 champion, verbatim).
//   bid: ky = bid % KS, ntp = bid / KS.
//   Partial tile (256x64 bf16, 32KB): Pb[(ky*NPAIR + ntp)*16384 + row*64 + c].
//   HOST INVARIANTS: kchunk % 64 == 0; KS*kchunk >= K; staged slabs fit lda.
// ===========================================================================
__global__ __launch_bounds__(256)
void gemm_bk64(const unsigned short* __restrict__ A, int lda,
               const float* __restrict__ B, int ldb,
               unsigned short* __restrict__ Pb,
               int NPAIR, int N, int K, int kchunk, int KS)
{
  __shared__ unsigned short As[256 * 72];
  __shared__ unsigned short Bs[64 * 72];
  const int bid = (int)blockIdx.x;
  const int ky = bid % KS, ntp = bid / KS;
  const int n0 = ntp << 6;
  const int t = threadIdx.x, lane = t & 63, w = t >> 6;
  const int lr = lane & 15, lk = lane >> 4;

  const int kstart = ky * kchunk;
  const int kend = min(K, kstart + kchunk);
  const int len = kend - kstart;
  const int nfull = (len > 0) ? (len >> 6) : 0;
  const int rem = (len > 0) ? (len & 63) : 0;

  const int ar = t >> 2, ac = t & 3;
  const int br = t >> 2, bq = t & 3;

  f4v acc[4][4] = {};
  float4 b_cur[4], b_nxt[4];

  auto loadB = [&](float4* dst, int kb) {
    const int row = n0 + br;
    if (row < N) {
      #pragma unroll
      for (int i = 0; i < 4; ++i)
        dst[i] = *(const float4*)(B + (size_t)row * ldb + kb + bq * 16 + i * 4);
    } else {
      #pragma unroll
      for (int i = 0; i < 4; ++i) { dst[i].x = dst[i].y = dst[i].z = dst[i].w = 0.f; }
    }
  };
  auto stageA = [&](int kb) {
    #pragma unroll
    for (int p = 0; p < 4; ++p) {
      const int row = ar + p * 64;
      const s8v v0 = *(const s8v*)(A + (size_t)row * lda + kb + ac * 16);
      const s8v v1 = *(const s8v*)(A + (size_t)row * lda + kb + ac * 16 + 8);
      *(s8v*)(As + row * 72 + ac * 16) = v0;
      *(s8v*)(As + row * 72 + ac * 16 + 8) = v1;
    }
  };
  auto stageB = [&](const float4* bv) {
    s8v p0, p1;
    p0[0] = (short)f2b(bv[0].x); p0[1] = (short)f2b(bv[0].y);
    p0[2] = (short)f2b(bv[0].z); p0[3] = (short)f2b(bv[0].w);
    p0[4] = (short)f2b(bv[1].x); p0[5] = (short)f2b(bv[1].y);
    p0[6] = (short)f2b(bv[1].z); p0[7] = (short)f2b(bv[1].w);
    p1[0] = (short)f2b(bv[2].x); p1[1] = (short)f2b(bv[2].y);
    p1[2] = (short)f2b(bv[2].z); p1[3] = (short)f2b(bv[2].w);
    p1[4] = (short)f2b(bv[3].x); p1[5] = (short)f2b(bv[3].y);
    p1[6] = (short)f2b(bv[3].z); p1[7] = (short)f2b(bv[3].w);
    *(s8v*)(Bs + br * 72 + bq * 16) = p0;
    *(s8v*)(Bs + br * 72 + bq * 16 + 8) = p1;
  };
  auto domfma = [&]() {
    #pragma unroll
    for (int ks = 0; ks < 2; ++ks) {
      s8v af[4], bf[4];
      #pragma unroll
      for (int fm = 0; fm < 4; ++fm)
        af[fm] = *(const s8v*)(As + (w * 64 + fm * 16 + lr) * 72 + ks * 32 + lk * 8);
      #pragma unroll
      for (int fn = 0; fn < 4; ++fn)
        bf[fn] = *(const s8v*)(Bs + (fn * 16 + lr) * 72 + ks * 32 + lk * 8);
      #pragma unroll
      for (int fm = 0; fm < 4; ++fm)
        #pragma unroll
        for (int fn = 0; fn < 4; ++fn)
          acc[fm][fn] = __builtin_amdgcn_mfma_f32_16x16x32_bf16(af[fm], bf[fn], acc[fm][fn], 0, 0, 0);
    }
  };

  int kb = kstart;
  if (nfull > 0) {
    loadB(b_cur, kb);
    for (int s = 0; s < nfull; ++s) {
      stageA(kb);
      stageB(b_cur);
      __syncthreads();
      const bool more = (s + 1 < nfull);
      if (more) loadB(b_nxt, kb + 64);
      domfma();
      __syncthreads();
      if (more) {
        #pragma unroll
        for (int i = 0; i < 4; ++i) b_cur[i] = b_nxt[i];
        kb += 64;
      }
    }
    kb += 64;
  }
  if (rem) {
    stageA(kb);
    {
      const int row = n0 + br;
      #pragma unroll
      for (int i = 0; i < 4; ++i) {
        float e[4];
        #pragma unroll
        for (int v = 0; v < 4; ++v) {
          const int c = kb + bq * 16 + i * 4 + v;
          e[v] = (row < N && c < kend) ? B[(size_t)row * ldb + c] : 0.f;
        }
        b_cur[i].x = e[0]; b_cur[i].y = e[1]; b_cur[i].z = e[2]; b_cur[i].w = e[3];
      }
    }
    stageB(b_cur);
    __syncthreads();
    domfma();
    __syncthreads();
  }

  unsigned short* Pt = Pb + ((size_t)ky * NPAIR + ntp) * 16384;
  #pragma unroll
  for (int fm = 0; fm < 4; ++fm)
    #pragma unroll
    for (int fn = 0; fn < 4; ++fn) {
      const int col = fn * 16 + lr;
      #pragma unroll
      for (int j = 0; j < 4; ++j) {
        const int row = w * 64 + fm * 16 + lk * 4 + j;
        Pt[row * 64 + col] = f2b(acc[fm][fn][j]);
      }
    }
}

// ===========================================================================
// Reduce bf16 partials + epilogue. Compile-time KS (unrolled -> KS loads in
// flight) and 8-way row split (grid NPAIR*8, 1.3 blocks/CU vs old 0.65).
// Block (ntp=bid>>3, qr=bid&7): rows qr*32..+32; thread: row qr*32+(t>>3),
// cols (t&7)*8..+8 (one s8v per ky).
// ===========================================================================
template<int KS, bool BN, bool RES, bool WRD, bool WRT>
__global__ __launch_bounds__(256)
void reduce_bk64(const unsigned short* __restrict__ Pb, int NPAIR, int N,
                 const float* __restrict__ bias,
                 const float* __restrict__ g, const float* __restrict__ bb,
                 const float* __restrict__ rm, const float* __restrict__ rv,
                 float* __restrict__ dR, int lddr,
                 unsigned short* __restrict__ Cb, int ldc,
                 unsigned short* __restrict__ htr)
{
  const int bid = (int)blockIdx.x;
  const int ntp = bid >> 3, qr = bid & 7;
  const int t = threadIdx.x;
  const int row = qr * 32 + (t >> 3);
  const int c0 = (t & 7) * 8;
  const int n0 = ntp << 6;

  float vv[8];
  #pragma unroll
  for (int e = 0; e < 8; ++e) vv[e] = 0.f;

  const unsigned short* base = Pb + (size_t)ntp * 16384 + row * 64 + c0;
  #pragma unroll
  for (int ky = 0; ky < KS; ++ky) {
    const s8v pa = *(const s8v*)(base + (size_t)ky * NPAIR * 16384);
    #pragma unroll
    for (int e = 0; e < 8; ++e) vv[e] += b2f((unsigned short)pa[e]);
  }

  unsigned short outp[8];
  #pragma unroll
  for (int e = 0; e < 8; ++e) {
    const int col = n0 + c0 + e;
    float v = 0.f;
    if (col < N) {
      v = vv[e] + bias[col];
      if (BN) { const float s = g[col] * rsqrtf(rv[col] + EPS); v = (v - rm[col]) * s + bb[col]; }
      v = fmaxf(v, 0.f);
      if (RES) v += dR[(size_t)row * lddr + col];
      if (WRD) dR[(size_t)row * lddr + col] = v;
      if (WRT) htr[(size_t)col * 256 + row] = f2b(v);
    }
    outp[e] = f2b(v);
  }
  if (!WRT)
    *(s8v*)(Cb + (size_t)row * ldc + n0 + c0) = *(const s8v*)(outp);
}

// ===========================================================================
// No-split-K GEMM with fused epilogue (W17/W18 only; r14-validated).
// ===========================================================================
template<bool F32OUT>
__global__ __launch_bounds__(256)
void gemm_direct(const unsigned short* __restrict__ A, int lda,
                 const float* __restrict__ B, int ldb,
                 const float* __restrict__ bias,
                 unsigned short* __restrict__ Cb, int ldc,
                 float* __restrict__ Cf, int N, int K)
{
  __shared__ unsigned short As[64 * 72];
  __shared__ unsigned short Bs[64 * 72];
  const int bid = (int)blockIdx.x;
  const int mr = bid & 3, nt = bid >> 2;
  const int m0 = mr << 6, n0 = nt << 6;
  const int t = threadIdx.x, lane = t & 63, w = t >> 6;
  const int lr = lane & 15, lk = lane >> 4;
  const int ar = t >> 2, ac = t & 3;
  const int br = t >> 2, bq = t & 3;

  const int nfull = K >> 6;
  const int rem = K & 63;

  f4v acc[4] = {};
  float4 b_cur[4], b_nxt[4];

  auto loadB = [&](float4* dst, int kb) {
    const int row = n0 + br;
    if (row < N) {
      #pragma unroll
      for (int i = 0; i < 4; ++i)
        dst[i] = *(const float4*)(B + (size_t)row * ldb + kb + bq * 16 + i * 4);
    } else {
      #pragma unroll
      for (int i = 0; i < 4; ++i) { dst[i].x = dst[i].y = dst[i].z = dst[i].w = 0.f; }
    }
  };
  auto stageA = [&](int kb) {
    const s8v v0 = *(const s8v*)(A + (size_t)(m0 + ar) * lda + kb + ac * 16);
    const s8v v1 = *(const s8v*)(A + (size_t)(m0 + ar) * lda + kb + ac * 16 + 8);
    *(s8v*)(As + ar * 72 + ac * 16) = v0;
    *(s8v*)(As + ar * 72 + ac * 16 + 8) = v1;
  };
  auto stageB = [&](const float4* bv) {
    s8v p0, p1;
    p0[0] = (short)f2b(bv[0].x); p0[1] = (short)f2b(bv[0].y);
    p0[2] = (short)f2b(bv[0].z); p0[3] = (short)f2b(bv[0].w);
    p0[4] = (short)f2b(bv[1].x); p0[5] = (short)f2b(bv[1].y);
    p0[6] = (short)f2b(bv[1].z); p0[7] = (short)f2b(bv[1].w);
    p1[0] = (short)f2b(bv[2].x); p1[1] = (short)f2b(bv[2].y);
    p1[2] = (short)f2b(bv[2].z); p1[3] = (short)f2b(bv[2].w);
    p1[4] = (short)f2b(bv[3].x); p1[5] = (short)f2b(bv[3].y);
    p1[6] = (short)f2b(bv[3].z); p1[7] = (short)f2b(bv[3].w);
    *(s8v*)(Bs + br * 72 + bq * 16) = p0;
    *(s8v*)(Bs + br * 72 + bq * 16 + 8) = p1;
  };
  auto domfma = [&]() {
    #pragma unroll
    for (int ks = 0; ks < 2; ++ks) {
      s8v af = *(const s8v*)(As + (w * 16 + lr) * 72 + ks * 32 + lk * 8);
      #pragma unroll
      for (int fn = 0; fn < 4; ++fn) {
        s8v bf = *(const s8v*)(Bs + (fn * 16 + lr) * 72 + ks * 32 + lk * 8);
        acc[fn] = __builtin_amdgcn_mfma_f32_16x16x32_bf16(af, bf, acc[fn], 0, 0, 0);
      }
    }
  };

  int kb = 0;
  if (nfull > 0) {
    loadB(b_cur, 0);
    for (int s = 0; s < nfull; ++s) {
      stageA(kb);
      stageB(b_cur);
      __syncthreads();
      const bool more = (s + 1 < nfull);
      if (more) loadB(b_nxt, kb + 64);
      domfma();
      __syncthreads();
      if (more) {
        #pragma unroll
        for (int i = 0; i < 4; ++i) b_cur[i] = b_nxt[i];
        kb += 64;
      }
    }
    kb += 64;
  }
  if (rem) {
    stageA(kb);
    {
      const int row = n0 + br;
      #pragma unroll
      for (int i = 0; i < 4; ++i) {
        float e[4];
        #pragma unroll
        for (int v = 0; v < 4; ++v) {
          const int c = kb + bq * 16 + i * 4 + v;
          e[v] = (row < N && c < K) ? B[(size_t)row * ldb + c] : 0.f;
        }
        b_cur[i].x = e[0]; b_cur[i].y = e[1]; b_cur[i].z = e[2]; b_cur[i].w = e[3];
      }
    }
    stageB(b_cur);
    __syncthreads();
    domfma();
    __syncthreads();
  }

  #pragma unroll
  for (int fn = 0; fn < 4; ++fn) {
    const int col = n0 + fn * 16 + lr;
    const bool cin = (col < N);
    #pragma unroll
    for (int j = 0; j < 4; ++j) {
      const int row = m0 + w * 16 + lk * 4 + j;
      float v = 0.f;
      if (cin) v = fmaxf(acc[fn][j] + bias[col], 0.f);
      if (F32OUT) { if (cin) Cf[(size_t)row * N + col] = v; }
      else Cb[(size_t)row * ldc + col] = f2b(v);
    }
  }
}

// ---------------------------------------------------------------------------
// Prep: pack x-geno to bf16, pack env rows, zero h5b pads (stride 13376).
// ---------------------------------------------------------------------------
__global__ __launch_bounds__(256)
void prep_k(const float* __restrict__ x, unsigned short* __restrict__ xg,
            unsigned short* __restrict__ envb, unsigned short* __restrict__ h5b)
{
  const int bid = (int)blockIdx.x, t = threadIdx.x;
  if (bid < 16384) {
    const int idx = bid * 256 + t;
    const int r = idx >> 14, c = idx & 16383;
    xg[idx] = f2b(x[(size_t)r * 16437 + c]);
  } else if (bid < 16456) {
    const int idx = (bid - 16384) * 256 + t;
    const int b = idx / 72, c = idx % 72;
    envb[idx] = (c < 53) ? f2b(x[(size_t)b * 16437 + 16384 + c]) : (unsigned short)0;
  } else {
    for (int z = t; z < 256 * 46; z += 256) {
      const int b = z / 46, j = z % 46;
      h5b[(size_t)b * 13376 + 13330 + j] = 0;
    }
  }
}

// ---------------------------------------------------------------------------
// Fused head: per unit i, 4 chained 256x64x64 GEMMs in LDS/regs (unchanged).
// ---------------------------------------------------------------------------
__global__ __launch_bounds__(256, 2)
void fused_head(const unsigned short* __restrict__ envb,
                const unsigned short* __restrict__ htr,
                const float* __restrict__ Wlin, const float* __restrict__ blin,
                const float* __restrict__ W13, const float* __restrict__ b13,
                const float* __restrict__ W14, const float* __restrict__ b14,
                const float* __restrict__ W15, const float* __restrict__ b15,
                const float* __restrict__ bn3g, const float* __restrict__ bn3b,
                const float* __restrict__ bn3rm, const float* __restrict__ bn3rv,
                unsigned short* __restrict__ h5b)
{
  __shared__ unsigned short act[256 * 72];
  __shared__ unsigned short Wl[64 * 72];
  __shared__ unsigned short Wa[64 * 72];
  __shared__ unsigned short Wb[16 * 72];
  const int i = (int)blockIdx.x;
  const int t = threadIdx.x, lane = t & 63, w = t >> 6;
  const int lr = lane & 15, lk = lane >> 4;
  const int R = 2666;

  #pragma unroll
  for (int c8 = 0; c8 < 9; ++c8)
    *(s8v*)(act + t * 72 + c8 * 8) = *(const s8v*)(envb + t * 72 + c8 * 8);
  act[t * 72 + 53] = htr[(size_t)i * 256 + t];

  const float* wli = Wlin + (size_t)i * 2916;
  for (int idx = t; idx < 64 * 72; idx += 256) {
    const int r = idx / 72, f = idx % 72;
    Wl[idx] = (r < 54 && f < 54) ? f2b(wli[r * 54 + f]) : (unsigned short)0;
    Wa[idx] = (r < 54 && f < 54) ? f2b(W13[r * 54 + f]) : (unsigned short)0;
  }
  for (int idx = t; idx < 16 * 72; idx += 256) {
    const int r = idx / 72, f = idx % 72;
    Wb[idx] = (r < 5 && f < 54) ? f2b(W15[r * 54 + f]) : (unsigned short)0;
  }
  const float s0 = bn3g[i] * rsqrtf(bn3rv[i] + EPS), m0 = bn3rm[i], c0 = bn3b[i];
  const float s1 = bn3g[R+i] * rsqrtf(bn3rv[R+i] + EPS), m1 = bn3rm[R+i], c1 = bn3b[R+i];
  const float s2 = bn3g[2*R+i] * rsqrtf(bn3rv[2*R+i] + EPS), m2 = bn3rm[2*R+i], c2 = bn3b[2*R+i];
  __syncthreads();

  const int abase = (w * 64 + lr) * 72 + lk * 8;
  f4v acc[4][4];

  auto zacc = [&]() {
    #pragma unroll
    for (int a = 0; a < 4; ++a)
      #pragma unroll
      for (int b = 0; b < 4; ++b) acc[a][b] = f4v{0.f, 0.f, 0.f, 0.f};
  };
  auto gemm4 = [&](const unsigned short* B) {
    s8v af[2][4];
    #pragma unroll
    for (int ks = 0; ks < 2; ++ks)
      #pragma unroll
      for (int fm = 0; fm < 4; ++fm)
        af[ks][fm] = *(const s8v*)(act + abase + fm * 16 * 72 + ks * 32);
    #pragma unroll
    for (int fn = 0; fn < 4; ++fn) {
      s8v b0 = *(const s8v*)(B + (fn * 16 + lr) * 72 + lk * 8);
      s8v b1 = *(const s8v*)(B + (fn * 16 + lr) * 72 + 32 + lk * 8);
      #pragma unroll
      for (int fm = 0; fm < 4; ++fm) {
        acc[fm][fn] = __builtin_amdgcn_mfma_f32_16x16x32_bf16(af[0][fm], b0, acc[fm][fn], 0, 0, 0);
        acc[fm][fn] = __builtin_amdgcn_mfma_f32_16x16x32_bf16(af[1][fm], b1, acc[fm][fn], 0, 0, 0);
      }
    }
  };
  auto epi_bn = [&](const float* bias, float s, float m, float c) {
    #pragma unroll
    for (int fn = 0; fn < 4; ++fn) {
      const int o = fn * 16 + lr;
      const float bo = (o < 54) ? bias[o] : 0.f;
      #pragma unroll
      for (int fm = 0; fm < 4; ++fm)
        #pragma unroll
        for (int j = 0; j < 4; ++j) {
          const int row = w * 64 + fm * 16 + lk * 4 + j;
          float v = acc[fm][fn][j] + bo;
          v = (v - m) * s + c;
          v = fmaxf(v, 0.f);
          act[row * 72 + o] = (o < 54) ? f2b(v) : (unsigned short)0;
        }
    }
  };

  zacc(); gemm4(Wl);
  #pragma unroll
  for (int fn = 0; fn < 4; ++fn) {
    const int o = fn * 16 + lr;
    const float bl = (o < 54) ? blin[(size_t)i * 54 + o] : 0.f;
    #pragma unroll
    for (int fm = 0; fm < 4; ++fm)
      #pragma unroll
      for (int j = 0; j < 4; ++j) {
        const int row = w * 64 + fm * 16 + lk * 4 + j;
        float v = acc[fm][fn][j] + bl;
        act[row * 72 + o] = (o < 54) ? f2b(v) : (unsigned short)0;
      }
  }
  __syncthreads();
  for (int idx = t; idx < 64 * 72; idx += 256) {
    const int r = idx / 72, f = idx % 72;
    Wl[idx] = (r < 54 && f < 54) ? f2b(W14[r * 54 + f]) : (unsigned short)0;
  }
  zacc(); gemm4(Wa); epi_bn(b13, s0, m0, c0);
  __syncthreads();
  zacc(); gemm4(Wl); epi_bn(b14, s1, m1, c1);
  f4v a4[4] = {};
  {
    s8v af[2][4];
    #pragma unroll
    for (int ks = 0; ks < 2; ++ks)
      #pragma unroll
      for (int fm = 0; fm < 4; ++fm)
        af[ks][fm] = *(const s8v*)(act + abase + fm * 16 * 72 + ks * 32);
    s8v b0 = *(const s8v*)(Wb + lr * 72 + lk * 8);
    s8v b1 = *(const s8v*)(Wb + lr * 72 + 32 + lk * 8);
    #pragma unroll
    for (int fm = 0; fm < 4; ++fm) {
      a4[fm] = __builtin_amdgcn_mfma_f32_16x16x32_bf16(af[0][fm], b0, a4[fm], 0, 0, 0);
      a4[fm] = __builtin_amdgcn_mfma_f32_16x16x32_bf16(af[1][fm], b1, a4[fm], 0, 0, 0);
    }
  }
  if (lr < 5) {
    const float b5 = b15[lr];
    #pragma unroll
    for (int fm = 0; fm < 4; ++fm)
      #pragma unroll
      for (int j = 0; j < 4; ++j) {
        const int row = w * 64 + fm * 16 + lk * 4 + j;
        float v = a4[fm][j] + b5;
        v = (v - m2) * s2 + c2;
        v = fmaxf(v, 0.f);
        h5b[(size_t)row * 13376 + (size_t)i * 5 + lr] = f2b(v);
      }
  }
}

extern "C" void kernel_launch(void* const* d_in, const int* in_sizes, int n_in,
                              void* d_out, int out_size, void* d_ws, size_t ws_size,
                              hipStream_t stream)
{
  const float* x    = (const float*)d_in[0];
  const float* W1   = (const float*)d_in[1];
  const float* b1   = (const float*)d_in[2];
  const float* Wmid = (const float*)d_in[3];
  const float* bmid = (const float*)d_in[4];
  const float* bng  = (const float*)d_in[5];
  const float* bnb  = (const float*)d_in[6];
  const float* bnrm = (const float*)d_in[7];
  const float* bnrv = (const float*)d_in[8];
  const float* Wlin = (const float*)d_in[9];
  const float* blin = (const float*)d_in[10];
  const float* W13  = (const float*)d_in[11];
  const float* b13  = (const float*)d_in[12];
  const float* W14  = (const float*)d_in[13];
  const float* b14  = (const float*)d_in[14];
  const float* W15  = (const float*)d_in[15];
  const float* b15  = (const float*)d_in[16];
  const float* bn3g = (const float*)d_in[17];
  const float* bn3b = (const float*)d_in[18];
  const float* bn3rm= (const float*)d_in[19];
  const float* bn3rv= (const float*)d_in[20];
  const float* W16  = (const float*)d_in[21];
  const float* b16  = (const float*)d_in[22];
  const float* W17  = (const float*)d_in[23];
  const float* b17  = (const float*)d_in[24];
  const float* W18  = (const float*)d_in[25];
  const float* b18  = (const float*)d_in[26];

  const int R = 2666;
  char* p = (char*)d_ws;
  unsigned short* xg  = (unsigned short*)p; p += (size_t)256 * 16384 * 2;
  unsigned short* hA  = (unsigned short*)p; p += (size_t)256 * 2688 * 2;
  unsigned short* hB  = (unsigned short*)p; p += (size_t)256 * 2688 * 2;
  float*          dR  = (float*)p;          p += (size_t)256 * 2688 * 4;
  unsigned short* h5b = (unsigned short*)p; p += (size_t)256 * 13376 * 2;
  unsigned short* h6b = (unsigned short*)p; p += (size_t)256 * 768 * 2;
  unsigned short* h7b = (unsigned short*)p; p += (size_t)256 * 768 * 2;
  unsigned short* envb= (unsigned short*)p; p += (size_t)256 * 72 * 2;
  unsigned short* htr = (unsigned short*)p; p += (size_t)2666 * 256 * 2;
  unsigned short* Pb  = (unsigned short*)p; // bf16 partials, <= 18.4 MB

  dim3 TB(256);

  prep_k<<<dim3(16457), TB, 0, stream>>>(x, xg, envb, h5b);

  // L1: K=16384, NPAIR=42, KS=8, kchunk=2048 (32 steps). Grid 336. + reduce.
  gemm_bk64<<<dim3(42 * 8), TB, 0, stream>>>(xg, 16384, W1, 16384, Pb, 42, R, 16384, 2048, 8);
  reduce_bk64<8, true, false, true, false><<<dim3(42 * 8), TB, 0, stream>>>(
      Pb, 42, R, b1, bng, bnb, bnrm, bnrv, dR, 2688, hA, 2688, nullptr);

  // mids: K=2666, NPAIR=42, KS=14, kchunk=192 (3 steps; ky=13: 2496..2666,
  // nfull=2, rem=42 -> slab 2624..2688 = lda). Grid 588. + reduce (grid 336).
  unsigned short* cur = hA; unsigned short* nxt = hB;
  for (int k = 0; k < 11; ++k) {
    const float* bw = Wmid + (size_t)k * R * R;
    const float* bs = bmid + (size_t)k * R;
    const int L = k + 1;
    gemm_bk64<<<dim3(42 * 14), TB, 0, stream>>>(cur, 2688, bw, R, Pb, 42, R, R, 192, 14);
    if (k == 10)
      reduce_bk64<14, true, false, false, true><<<dim3(42 * 8), TB, 0, stream>>>(
          Pb, 42, R, bs, bng + (size_t)L * R, bnb + (size_t)L * R,
          bnrm + (size_t)L * R, bnrv + (size_t)L * R,
          nullptr, 0, nullptr, 2688, htr);
    else if ((k & 1) == 0)
      reduce_bk64<14, true, false, false, false><<<dim3(42 * 8), TB, 0, stream>>>(
          Pb, 42, R, bs, bng + (size_t)L * R, bnb + (size_t)L * R,
          bnrm + (size_t)L * R, bnrv + (size_t)L * R,
          nullptr, 0, nxt, 2688, nullptr);
    else
      reduce_bk64<14, true, true, true, false><<<dim3(42 * 8), TB, 0, stream>>>(
          Pb, 42, R, bs, bng + (size_t)L * R, bnb + (size_t)L * R,
          bnrm + (size_t)L * R, bnrv + (size_t)L * R,
          dR, 2688, nxt, 2688, nullptr);
    unsigned short* tmp = cur; cur = nxt; nxt = tmp;
  }

  // Fused d3 -> W13 -> W14 -> W15 chain
  fused_head<<<dim3(2666), TB, 0, stream>>>(
      envb, htr, Wlin, blin, W13, b13, W14, b14, W15, b15,
      bn3g, bn3b, bn3rm, bn3rv, h5b);

  // W16: K=13330, NPAIR=12, KS=15, kchunk=896 (15*896=13440 >= 13330; ky=14:
  // 12544..13330, nfull=12, rem=18 -> slab 13312..13376 = lda). Grid 180.
  gemm_bk64<<<dim3(12 * 15), TB, 0, stream>>>(h5b, 13376, W16, 13330, Pb, 12, 750, 13330, 896, 15);
  reduce_bk64<15, false, false, false, false><<<dim3(12 * 8), TB, 0, stream>>>(
      Pb, 12, 750, b16, nullptr, nullptr, nullptr, nullptr,
      nullptr, 0, h6b, 768, nullptr);

  // W17: no-split direct (K=750, lda 768: nfull=11, rem=46, slab 704..768 ok).
  gemm_direct<false><<<dim3(4 * 12), TB, 0, stream>>>(
      h6b, 768, W17, 750, b17, h7b, 768, nullptr, 750, 750);

  // W18: no-split direct -> f32 d_out.
  gemm_direct<true><<<dim3(4 * 12), TB, 0, stream>>>(
      h7b, 768, W18, 750, b18, nullptr, 768, (float*)d_out, 750, 750);
}